// Round 5
// baseline (433.401 us; speedup 1.0000x reference)
//
#include <hip/hip_runtime.h>

// Problem constants
#define TT 128    // time points
#define DD 64     // state dim
#define HH 256    // f-net hidden
#define HKD 128   // kernel-net hidden
#define HD (HKD*DD)   // 8192

// ---------------------------------------------------------------------------
// k_init — no-upstream-dependency work, traffic-minimal:
//   b in [32,544): A[i][j][h] = w_ij * tanh(t_i*wk0 + t_j*wk1 + bk)   (8 MB write)
//   b in [0,32)  : f0 = f(z0) (redundant, cheap); M0 slice of 256 (Wk2 read 2 MB
//                  total across blocks); b==0 also bF0; all zero their Gb slice.
// ---------------------------------------------------------------------------
__global__ void __launch_bounds__(256)
k_init(const float* __restrict__ z0, const float* __restrict__ t,
       const float* __restrict__ W1, const float* __restrict__ b1,
       const float* __restrict__ W2, const float* __restrict__ b2,
       const float* __restrict__ Wk1, const float* __restrict__ bk1,
       const float* __restrict__ Wk2, const float* __restrict__ bk2,
       float* __restrict__ A, float* __restrict__ M0,
       float* __restrict__ bF0, float* __restrict__ Gz)
{
    const int b = blockIdx.x, tid = threadIdx.x;
    const float dt = t[1] - t[0];

    if (b >= 32) {
        // ---- A precompute: 4096 entries/block; i = (b-32)>>2 block-constant
        const int ab = b - 32;
        const int h = tid & 127;
        const float wk0 = Wk1[h], wk1v = Wk1[HKD + h], bk = bk1[h];
        const int i = ab >> 2;
        const float ti = t[i];
        const int base = ab * 4096;
        #pragma unroll 4
        for (int k = 0; k < 16; ++k) {
            int n = base + k * 256 + tid;
            int j = (n >> 7) & 127;
            float w = (i == 0 || j > i) ? 0.f : dt * ((j == 0 || j == i) ? 0.5f : 1.f);
            float v = 0.f;
            if (w != 0.f)   // wave-uniform (j constant within a wave)
                v = w * tanhf(ti * wk0 + t[j] * wk1v + bk);
            A[n] = v;
        }
        return;
    }

    // ---- M0 blocks (proven r2/r3 P0 logic)
    const int part = tid >> 6, d = tid & 63;
    __shared__ float red[4][64];
    __shared__ float ys[DD];
    __shared__ float hs[HH];
    __shared__ __attribute__((aligned(16))) float fs[DD];

    if (tid < DD) ys[tid] = z0[tid];
    __syncthreads();
    float acc = b1[tid];
    #pragma unroll 8
    for (int e = 0; e < DD; ++e) acc += ys[e] * W1[e * HH + tid];
    hs[tid] = tanhf(acc);
    __syncthreads();
    {
        float s = 0.f;
        #pragma unroll 8
        for (int h = part * 64; h < part * 64 + 64; ++h) s += hs[h] * W2[h * DD + d];
        red[part][d] = s;
    }
    __syncthreads();
    if (part == 0)
        fs[d] = b2[d] + red[0][d] + red[1][d] + red[2][d] + red[3][d];
    __syncthreads();

    if (b == 0) {   // bF0[d] = bk2[d,:] . f0   (block-uniform branch)
        float s = 0.f;
        #pragma unroll
        for (int e = part * 16; e < part * 16 + 16; ++e) s += bk2[d * DD + e] * fs[e];
        red[part][d] = s;
        __syncthreads();
        if (part == 0)
            bF0[d] = red[0][d] + red[1][d] + red[2][d] + red[3][d];
    }

    // M0 slice: hd = h*64+d -> Wk2 offset hd*64 (== (hd>>6)*4096 + (hd&63)*64)
    {
        int hd = b * 256 + tid;
        const float* Wrow = Wk2 + (size_t)hd * DD;
        float a = 0.f;
        #pragma unroll
        for (int e = 0; e < DD; e += 8) {
            float4 wa = *(const float4*)(Wrow + e);
            float4 wb = *(const float4*)(Wrow + e + 4);
            float4 fa = *(const float4*)&fs[e];
            float4 fb = *(const float4*)&fs[e + 4];
            a += fa.x*wa.x + fa.y*wa.y + fa.z*wa.z + fa.w*wa.w
               + fb.x*wb.x + fb.y*wb.y + fb.z*wb.z + fb.w*wb.w;
        }
        M0[hd] = a;
    }
    Gz[b * 256 + tid] = 0.f;   // zero Gb for it1's atomics (32*256 = 8192)
}

// ---------------------------------------------------------------------------
// k_G0 — it0 G (proven r3 P1): G_i[d] = sum_h B[i,h]*M0[h,d] + dt*i*bF0[d],
// B[i,h] = rowsum_j A[i,j,h] (A rows are pre-weighted, zero for j>i).
// ---------------------------------------------------------------------------
__global__ void __launch_bounds__(256)
k_G0(const float* __restrict__ t, const float* __restrict__ A,
     const float* __restrict__ M0, const float* __restrict__ bF0,
     float* __restrict__ G)
{
    const int i = blockIdx.x, tid = threadIdx.x;
    const int part = tid >> 6, d = tid & 63;
    __shared__ float Bpart[2][HKD];
    __shared__ float Bs[HKD];
    __shared__ float red[4][64];
    const float dt = t[1] - t[0];
    const int h = tid & 127, half = tid >> 7;
    float bsum = 0.f;
    const float* Ai = A + (size_t)i * (TT * HKD);
    for (int j = half; j <= i; j += 2) bsum += Ai[j * HKD + h];
    Bpart[half][h] = bsum;
    __syncthreads();
    if (tid < HKD) Bs[tid] = Bpart[0][tid] + Bpart[1][tid];
    __syncthreads();
    float a = 0.f;
    #pragma unroll 8
    for (int h2 = part * 32; h2 < part * 32 + 32; ++h2) a += Bs[h2] * M0[h2 * DD + d];
    red[part][d] = a;
    __syncthreads();
    if (part == 0) {
        float g = red[0][d] + red[1][d] + red[2][d] + red[3][d];
        if (i > 0) g += dt * (float)i * bF0[d];
        G[i * DD + d] = g;
    }
}

// ---------------------------------------------------------------------------
// k_FM — fused F+M, traffic-minimal. grid (16 hd-slices of 512, 8 j-tiles of 16).
// Per block: 16 MLPs (f_j staged in LDS), bF (hs==0), M slice (Wk2 row held in
// 64 VGPRs, amortized over the 16 j's). seed_out: block(0,0) writes out = z0.
// ---------------------------------------------------------------------------
__global__ void __launch_bounds__(256)
k_FM(const float* __restrict__ Gin, const float* __restrict__ z0,
     const float* __restrict__ t,
     const float* __restrict__ W1, const float* __restrict__ b1,
     const float* __restrict__ W2, const float* __restrict__ b2,
     const float* __restrict__ bk2, const float* __restrict__ Wk2,
     float* __restrict__ M, float* __restrict__ bF,
     float* __restrict__ out, int seed_out)
{
    const int hs = blockIdx.x, jt = blockIdx.y, tid = threadIdx.x;
    const int part = tid >> 6, d = tid & 63;
    __shared__ float red[4][64];
    __shared__ float ys[DD];
    __shared__ float hsm[HH];
    __shared__ __attribute__((aligned(16))) float fs[16][DD];
    const float dt = t[1] - t[0];
    const int j0 = jt * 16;

    for (int r = 0; r < 16; ++r) {
        const int j = j0 + r;
        // y_j = z0 + dt*trap(Gin[0..j])
        float s = 0.f;
        if (j > 0) {
            for (int jp = part; jp <= j; jp += 4) {
                float w = (jp == 0 || jp == j) ? 0.5f : 1.0f;
                s += w * Gin[jp * DD + d];
            }
        }
        red[part][d] = s;
        __syncthreads();
        if (part == 0)
            ys[d] = z0[d] + dt * (red[0][d] + red[1][d] + red[2][d] + red[3][d]);
        __syncthreads();
        // f_j = tanh(y@W1+b1)@W2+b2
        float acc = b1[tid];
        #pragma unroll 8
        for (int e = 0; e < DD; ++e) acc += ys[e] * W1[e * HH + tid];
        hsm[tid] = tanhf(acc);
        __syncthreads();
        float s2 = 0.f;
        #pragma unroll 8
        for (int h = part * 64; h < part * 64 + 64; ++h) s2 += hsm[h] * W2[h * DD + d];
        red[part][d] = s2;
        __syncthreads();
        if (part == 0)
            fs[r][d] = b2[d] + red[0][d] + red[1][d] + red[2][d] + red[3][d];
        __syncthreads();
    }

    if (hs == 0) {   // bF[j0+rr, d] = bk2[d,:] . f_{j0+rr}
        for (int rr = part; rr < 16; rr += 4) {
            const float* br = bk2 + (size_t)d * DD;
            float bf = 0.f;
            #pragma unroll
            for (int e = 0; e < DD; e += 8) {
                float4 wa = *(const float4*)(br + e);
                float4 wb = *(const float4*)(br + e + 4);
                float4 fa = *(const float4*)&fs[rr][e];
                float4 fb = *(const float4*)&fs[rr][e + 4];
                bf += fa.x*wa.x + fa.y*wa.y + fa.z*wa.z + fa.w*wa.w
                    + fb.x*wb.x + fb.y*wb.y + fb.z*wb.z + fb.w*wb.w;
            }
            bF[(j0 + rr) * DD + d] = bf;
        }
        if (seed_out && jt == 0 && tid < DD) out[tid] = z0[tid];
    }

    // M slice: hd in [hs*512, hs*512+512), 2 per thread; Wrow in registers.
    #pragma unroll
    for (int hh = 0; hh < 2; ++hh) {
        const int hd = hs * 512 + hh * 256 + tid;
        const float* Wrow = Wk2 + (size_t)hd * DD;
        float4 wv[16];
        #pragma unroll
        for (int k = 0; k < 16; ++k) wv[k] = *(const float4*)(Wrow + k * 4);
        #pragma unroll 4
        for (int r = 0; r < 16; ++r) {
            float a = 0.f;
            #pragma unroll
            for (int k = 0; k < 16; ++k) {
                float4 fv = *(const float4*)&fs[r][k * 4];
                a += fv.x*wv[k].x + fv.y*wv[k].y + fv.z*wv[k].z + fv.w*wv[k].w;
            }
            M[(size_t)(j0 + r) * HD + hd] = a;
        }
    }
}

// ---------------------------------------------------------------------------
// k_G1a — fused G1+Gfin (proven r4). grid (16 itiles, 64 chunks), active iff
// c<=4*itile+3. final==0: atomicAdd partials into Gout (pre-zeroed) + bF term.
// final==1: fold the output trapezoid: one atomicAdd per (block,d) into out
// (seeded = z0 by the preceding k_FM).
// ---------------------------------------------------------------------------
__global__ void __launch_bounds__(256)
k_G1a(const float* __restrict__ A, const float* __restrict__ M,
      const float* __restrict__ bF, const float* __restrict__ t,
      float* __restrict__ Gout, float* __restrict__ out, int final_it)
{
    const int itile = blockIdx.x, c = blockIdx.y;
    if (c > 4 * itile + 3) return;
    __shared__ __attribute__((aligned(16))) float As[8 * 256];
    __shared__ float red[4][8][64];
    const int tid = threadIdx.x, part = tid >> 6, d = tid & 63;
    const float dt = t[1] - t[0];

    const float* Asrc = A + ((size_t)(itile * 8) * TT + 2 * c) * HKD;
    for (int qq = tid; qq < 8 * 64; qq += 256) {      // 8 rows x 256 floats
        int r = qq >> 6, c4 = qq & 63;
        ((float4*)As)[r * 64 + c4] = *(const float4*)(Asrc + (size_t)r * TT * HKD + c4 * 4);
    }
    __syncthreads();

    float acc[8] = {0.f,0.f,0.f,0.f,0.f,0.f,0.f,0.f};
    const float* Mp = M + ((size_t)c * 256) * DD + d;
    const int jl0 = part * 64;
    for (int jl = jl0; jl < jl0 + 64; jl += 8) {
        float m0 = Mp[(size_t)(jl + 0) * DD];
        float m1 = Mp[(size_t)(jl + 1) * DD];
        float m2 = Mp[(size_t)(jl + 2) * DD];
        float m3 = Mp[(size_t)(jl + 3) * DD];
        float m4 = Mp[(size_t)(jl + 4) * DD];
        float m5 = Mp[(size_t)(jl + 5) * DD];
        float m6 = Mp[(size_t)(jl + 6) * DD];
        float m7 = Mp[(size_t)(jl + 7) * DD];
        #pragma unroll
        for (int r = 0; r < 8; ++r) {
            float4 a0 = *(const float4*)&As[r * 256 + jl];
            float4 a1 = *(const float4*)&As[r * 256 + jl + 4];
            acc[r] += a0.x*m0 + a0.y*m1 + a0.z*m2 + a0.w*m3
                    + a1.x*m4 + a1.y*m5 + a1.z*m6 + a1.w*m7;
        }
    }
    #pragma unroll
    for (int r = 0; r < 8; ++r) red[part][r][d] = acc[r];
    __syncthreads();
    if (part == 0) {
        if (!final_it) {
            #pragma unroll
            for (int r = 0; r < 8; ++r) {
                float v = red[0][r][d] + red[1][r][d] + red[2][r][d] + red[3][r][d];
                atomicAdd(&Gout[(itile * 8 + r) * DD + d], v);
            }
            if (c == 0) {   // dt*trap(bF[0..i]) term, once per row
                const int i0 = itile * 8;
                float run = 0.5f * bF[d];
                int p = 0;
                for (int r = 0; r < 8; ++r) {
                    int i = i0 + r;
                    if (i == 0) continue;
                    while (p < i - 1) { ++p; run += bF[p * DD + d]; }
                    float term = dt * (run + 0.5f * bF[i * DD + d]);
                    atomicAdd(&Gout[i * DD + d], term);
                }
            }
        } else {
            // out += dt * sum_r w_i * G-contribution  (w: 0.5 at i=0,127)
            float vsum = 0.f;
            #pragma unroll
            for (int r = 0; r < 8; ++r) {
                int i = itile * 8 + r;
                float w = (i == 0 || i == TT - 1) ? 0.5f : 1.0f;
                vsum += w * (red[0][r][d] + red[1][r][d] + red[2][r][d] + red[3][r][d]);
            }
            if (c == 0) {
                const int i0 = itile * 8;
                float run = 0.5f * bF[d];
                int p = 0;
                for (int r = 0; r < 8; ++r) {
                    int i = i0 + r;
                    if (i == 0) continue;
                    while (p < i - 1) { ++p; run += bF[p * DD + d]; }
                    float term = dt * (run + 0.5f * bF[i * DD + d]);
                    float w = (i == TT - 1) ? 0.5f : 1.0f;   // i>0 here
                    vsum += w * term;
                }
            }
            atomicAdd(&out[d], dt * vsum);
        }
    }
}

extern "C" void kernel_launch(void* const* d_in, const int* in_sizes, int n_in,
                              void* d_out, int out_size, void* d_ws, size_t ws_size,
                              hipStream_t stream) {
    const float* z0  = (const float*)d_in[0];
    const float* t   = (const float*)d_in[1];
    const float* W1  = (const float*)d_in[2];
    const float* b1  = (const float*)d_in[3];
    const float* W2  = (const float*)d_in[4];
    const float* b2  = (const float*)d_in[5];
    const float* Wk1 = (const float*)d_in[6];
    const float* bk1 = (const float*)d_in[7];
    const float* Wk2 = (const float*)d_in[8];
    const float* bk2 = (const float*)d_in[9];
    float* out = (float*)d_out;

    float* ws  = (float*)d_ws;
    float* A   = ws;                        // T*T*HK = 2,097,152 floats (8 MB)
    float* M   = A   + (size_t)TT*TT*HKD;   // T*HK*D = 1,048,576 (4 MB)
    float* M0  = M   + (size_t)TT*HKD*DD;   // HD = 8192
    float* bF0 = M0  + HD;                  // DD
    float* Ga  = bF0 + DD;                  // T*D
    float* Gb  = Ga  + TT*DD;               // T*D
    float* bF  = Gb  + TT*DD;               // T*D

    // 6 launches; stream order provides cross-XCD coherence (gap ~14us each,
    // vs ~33us for an in-kernel grid barrier — r2/r3 measurements).
    k_init<<<544, 256, 0, stream>>>(z0, t, W1, b1, W2, b2, Wk1, bk1, Wk2, bk2,
                                    A, M0, bF0, Gb);
    k_G0<<<TT, 256, 0, stream>>>(t, A, M0, bF0, Ga);
    // it1: Ga -> (F,M,bF) -> Gb
    k_FM<<<dim3(16, 8), 256, 0, stream>>>(Ga, z0, t, W1, b1, W2, b2, bk2, Wk2,
                                          M, bF, out, 0);
    k_G1a<<<dim3(16, 64), 256, 0, stream>>>(A, M, bF, t, Gb, out, 0);
    // it2: Gb -> (F,M,bF; seed out=z0) -> out
    k_FM<<<dim3(16, 8), 256, 0, stream>>>(Gb, z0, t, W1, b1, W2, b2, bk2, Wk2,
                                          M, bF, out, 1);
    k_G1a<<<dim3(16, 64), 256, 0, stream>>>(A, M, bF, t, Gb, out, 1);
}

// Round 6
// 257.784 us; speedup vs baseline: 1.6813x; 1.6813x over previous
//
#include <hip/hip_runtime.h>

// Problem constants
#define TT 128    // time points
#define DD 64     // state dim
#define HH 256    // f-net hidden
#define HKD 128   // kernel-net hidden
#define HD (HKD*DD)   // 8192
#define NB 512        // 2 blocks/CU, co-resident (proven by r3 completing)

// ---- relaxed agent-scope atomic access: coherent at the coherence point,
// ---- no fences needed (write-through stores / cache-bypassing loads).
__device__ __forceinline__ float ald(const float* p) {
    return __hip_atomic_load(const_cast<float*>(p), __ATOMIC_RELAXED, __HIP_MEMORY_SCOPE_AGENT);
}
__device__ __forceinline__ void ast(float* p, float v) {
    __hip_atomic_store(p, v, __ATOMIC_RELAXED, __HIP_MEMORY_SCOPE_AGENT);
}
__device__ __forceinline__ int aldi(int* p) {
    return __hip_atomic_load(p, __ATOMIC_RELAXED, __HIP_MEMORY_SCOPE_AGENT);
}

// Shared memory union — max member (scan) = 32 KB. 160/32 = 5 blocks/CU >= 2. OK.
union __attribute__((aligned(16))) SharedU {
    struct { float red[4][64]; float ys[DD]; float hs[HH]; float fs[DD]; } f;   // MLP
    struct { float Bpart[2][HKD]; float Bs[HKD]; float red[4][64]; } g0;        // it0 G
    struct { float Fs[8][DD]; } m;                                              // M phase
    struct { float As[8 * 256]; float red[4][8][64]; } g1;                      // G1a
    struct { float bFs[TT][DD]; } scan;                                         // bFint scan
};

// ---------------------------------------------------------------------------
// Fence-free counter barrier. Protocol soundness: __syncthreads() makes every
// wave drain vmcnt(0) -> all the block's write-through atomic stores have
// COMPLETED at the coherence point before tid0's counter add is issued. Any
// block that observes the counter therefore observes the data (same coherence
// point). asm memory clobbers stop compiler reordering; relaxed HW order is
// fine because all cross-block ordering goes through this protocol.
// 8 split sub-counters kill arrival contention (64 adds each).
// ---------------------------------------------------------------------------
__device__ __forceinline__ void cbar(int* cnt8, int b, int tid) {
    __syncthreads();
    asm volatile("" ::: "memory");
    if (tid == 0)
        __hip_atomic_fetch_add(&cnt8[b & 7], 1, __ATOMIC_RELAXED, __HIP_MEMORY_SCOPE_AGENT);
    if (tid < 8) {
        while (aldi(&cnt8[tid]) < NB / 8)
            __builtin_amdgcn_s_sleep(1);
    }
    asm volatile("" ::: "memory");
    __syncthreads();
}

// f-MLP: requires sm.f.ys valid (+synced); leaves f(y) in sm.f.fs (synced).
// W1/W2/b1/b2 are read-only inputs -> normal cached loads.
__device__ __forceinline__ void mlp_f(SharedU& sm, int tid,
                                      const float* __restrict__ W1, const float* __restrict__ b1,
                                      const float* __restrict__ W2, const float* __restrict__ b2) {
    int part = tid >> 6, d = tid & 63;
    float acc = b1[tid];
    #pragma unroll 8
    for (int e = 0; e < DD; ++e) acc += sm.f.ys[e] * W1[e * HH + tid];
    sm.f.hs[tid] = tanhf(acc);
    __syncthreads();
    float s = 0.f;
    #pragma unroll 8
    for (int h = part * 64; h < part * 64 + 64; ++h) s += sm.f.hs[h] * W2[h * DD + d];
    sm.f.red[part][d] = s;
    __syncthreads();
    if (part == 0)
        sm.f.fs[d] = b2[d] + sm.f.red[0][d] + sm.f.red[1][d] + sm.f.red[2][d] + sm.f.red[3][d];
    __syncthreads();
}

extern "C" __global__ void __launch_bounds__(256, 2)
mega(const float* __restrict__ z0, const float* __restrict__ t,
     const float* __restrict__ W1, const float* __restrict__ b1,
     const float* __restrict__ W2, const float* __restrict__ b2,
     const float* __restrict__ Wk1, const float* __restrict__ bk1,
     const float* __restrict__ Wk2, const float* __restrict__ bk2,
     float* __restrict__ M, float* __restrict__ M0, float* __restrict__ bF0,
     float* __restrict__ Ga, float* __restrict__ fbuf, float* __restrict__ bFb,
     float* __restrict__ bFint, float* __restrict__ Gb,
     int* cnt, float* __restrict__ out)
{
    const int b = blockIdx.x, tid = threadIdx.x;
    const int part = tid >> 6, d = tid & 63;
    __shared__ SharedU sm;
    const float dt = t[1] - t[0];
    int* m0cnt = cnt;        // single counter, target 32
    int* bars  = cnt + 8;    // 6 barriers x 8 sub-counters

    // ===================== Pa: M0 (blocks 0-31) || G0 (blocks 32-159) ========
    if (b < 32) {
        // f0 = f(z0)
        if (tid < DD) sm.f.ys[tid] = z0[tid];
        __syncthreads();
        mlp_f(sm, tid, W1, b1, W2, b2);
        if (b == 0) {   // bF0[d] = bk2[d,:] . f0
            float s = 0.f;
            #pragma unroll
            for (int e = part * 16; e < part * 16 + 16; ++e) s += bk2[d * DD + e] * sm.f.fs[e];
            sm.f.red[part][d] = s;
            __syncthreads();
            if (part == 0)
                ast(&bF0[d], sm.f.red[0][d] + sm.f.red[1][d] + sm.f.red[2][d] + sm.f.red[3][d]);
        }
        // M0 slice: hd -> Wk2 offset hd*64
        {
            int hd = b * 256 + tid;
            const float* Wrow = Wk2 + (size_t)hd * DD;
            float a = 0.f;
            #pragma unroll
            for (int e = 0; e < DD; e += 8) {
                float4 wa = *(const float4*)(Wrow + e);
                float4 wb = *(const float4*)(Wrow + e + 4);
                float4 fa = *(const float4*)&sm.f.fs[e];
                float4 fb = *(const float4*)&sm.f.fs[e + 4];
                a += fa.x*wa.x + fa.y*wa.y + fa.z*wa.z + fa.w*wa.w
                   + fb.x*wb.x + fb.y*wb.y + fb.z*wb.z + fb.w*wb.w;
            }
            ast(&M0[hd], a);
        }
        __syncthreads();                    // drain ast stores (vmcnt) ...
        asm volatile("" ::: "memory");
        if (tid == 0)                       // ... then signal M0 ready
            __hip_atomic_fetch_add(m0cnt, 1, __ATOMIC_RELAXED, __HIP_MEMORY_SCOPE_AGENT);
    } else if (b < 160) {
        const int i = b - 32;
        // B-row via on-the-fly tanh (overlaps with M0 blocks)
        {
            const int h = tid & 127, half = tid >> 7;
            float bsum = 0.f;
            if (i > 0) {
                const float wk0 = Wk1[h], wk1v = Wk1[HKD + h], bk = bk1[h];
                const float ti = t[i];
                for (int j = half; j <= i; j += 2) {
                    float w = dt * ((j == 0 || j == i) ? 0.5f : 1.0f);
                    bsum += w * tanhf(ti * wk0 + t[j] * wk1v + bk);
                }
            }
            sm.g0.Bpart[half][h] = bsum;
        }
        __syncthreads();
        if (tid < HKD) sm.g0.Bs[tid] = sm.g0.Bpart[0][tid] + sm.g0.Bpart[1][tid];
        // wait for M0
        if (tid == 0) { while (aldi(m0cnt) < 32) __builtin_amdgcn_s_sleep(1); }
        asm volatile("" ::: "memory");
        __syncthreads();
        float a = 0.f;
        #pragma unroll 8
        for (int h2 = part * 32; h2 < part * 32 + 32; ++h2)
            a += sm.g0.Bs[h2] * ald(&M0[h2 * DD + d]);
        sm.g0.red[part][d] = a;
        __syncthreads();
        if (part == 0) {
            float g = sm.g0.red[0][d] + sm.g0.red[1][d] + sm.g0.red[2][d] + sm.g0.red[3][d];
            g += dt * (float)i * ald(&bF0[d]);
            ast(&Ga[i * DD + d], (i == 0) ? 0.f : g);
        }
    } else if (b == 160) {
        if (tid < DD) ast(&out[tid], z0[tid]);   // seed out = z0 (final adds in P7)
    }
    cbar(bars + 0, b, tid);

    // ===================== iterations ========================================
    for (int it = 1; it <= 2; ++it) {
        const int fin = (it == 2);
        const float* Gin = (it == 1) ? Ga : Gb;

        // --- F: blocks 0-127, one MLP each (max parallelism, r9 structure) ---
        if (b < TT) {
            const int j = b;
            float s = 0.f;
            #pragma unroll 8
            for (int jp = part; jp < TT; jp += 4) {   // fixed trip count: loads batch
                float w = (j == 0 || jp > j) ? 0.f : ((jp == 0 || jp == j) ? 0.5f : 1.0f);
                s += w * ald(&Gin[jp * DD + d]);
            }
            sm.f.red[part][d] = s;
            __syncthreads();
            if (part == 0)
                sm.f.ys[d] = z0[d] + dt * (sm.f.red[0][d] + sm.f.red[1][d] + sm.f.red[2][d] + sm.f.red[3][d]);
            __syncthreads();
            mlp_f(sm, tid, W1, b1, W2, b2);
            if (part == 0) ast(&fbuf[j * DD + d], sm.f.fs[d]);
            float s2 = 0.f;
            #pragma unroll
            for (int e = part * 16; e < part * 16 + 16; ++e) s2 += bk2[d * DD + e] * sm.f.fs[e];
            sm.f.red[part][d] = s2;
            __syncthreads();
            if (part == 0)
                ast(&bFb[j * DD + d], sm.f.red[0][d] + sm.f.red[1][d] + sm.f.red[2][d] + sm.f.red[3][d]);
        }
        cbar(bars + 8 * (it == 1 ? 1 : 4), b, tid);

        // --- M: 512 units = (32 hd-chunks x 16 j-tiles of 8). Wk2 cached. ---
        {
            const int hd = (b & 31) * 256 + tid;
            const int j0 = (b >> 5) * 8;
            for (int k2 = tid; k2 < 8 * DD; k2 += 256)
                sm.m.Fs[k2 >> 6][k2 & 63] = ald(&fbuf[j0 * DD + k2]);
            __syncthreads();
            float acc[8] = {0.f,0.f,0.f,0.f,0.f,0.f,0.f,0.f};
            const float* Wrow = Wk2 + (size_t)hd * DD;
            for (int e = 0; e < DD; e += 8) {
                float4 wa = *(const float4*)(Wrow + e);
                float4 wb = *(const float4*)(Wrow + e + 4);
                #pragma unroll
                for (int r = 0; r < 8; ++r) {
                    float4 f0 = *(const float4*)&sm.m.Fs[r][e];
                    float4 f1 = *(const float4*)&sm.m.Fs[r][e + 4];
                    acc[r] += f0.x*wa.x + f0.y*wa.y + f0.z*wa.z + f0.w*wa.w
                            + f1.x*wb.x + f1.y*wb.y + f1.z*wb.z + f1.w*wb.w;
                }
            }
            #pragma unroll
            for (int r = 0; r < 8; ++r) ast(&M[(size_t)(j0 + r) * HD + hd], acc[r]);
        }
        // block 0 also computes bFint[i,d] = dt*trap(bFb[0..i]) via LDS scan
        if (b == 0) {
            __syncthreads();
            for (int idx = tid; idx < TT * DD; idx += 256)
                sm.scan.bFs[idx >> 6][idx & 63] = ald(&bFb[idx]);
            __syncthreads();
            if (tid < DD) {
                float run = 0.5f * sm.scan.bFs[0][tid];
                ast(&bFint[tid], 0.f);
                for (int i = 1; i < TT; ++i) {
                    float v = sm.scan.bFs[i][tid];
                    ast(&bFint[i * DD + tid], dt * (run + 0.5f * v));
                    run += v;
                }
            }
        }
        cbar(bars + 8 * (it == 1 ? 2 : 5), b, tid);

        // --- G1a: 544 units (blocks 0-31 take a second). A-tile tanh'd on the fly. ---
        for (int u = b; u < 544; u += NB) {
            int uu = u, itile = 0;
            while (uu >= 4 * (itile + 1)) { uu -= 4 * (itile + 1); ++itile; }
            const int c = uu;                 // c <= 4*itile+3 by construction
            __syncthreads();                  // protect As/red reuse across units
            {
                const int h = tid & 127;
                const int j = 2 * c + (tid >> 7);
                const float wk0 = Wk1[h], wk1v = Wk1[HKD + h], bk = bk1[h];
                const float tj = t[j];
                #pragma unroll
                for (int k = 0; k < 8; ++k) {
                    int i = itile * 8 + k;
                    float w = (i == 0 || j > i) ? 0.f : dt * ((j == 0 || j == i) ? 0.5f : 1.0f);
                    sm.g1.As[k * 256 + tid] = w * tanhf(t[i] * wk0 + tj * wk1v + bk);
                }
            }
            __syncthreads();
            float acc[8] = {0.f,0.f,0.f,0.f,0.f,0.f,0.f,0.f};
            const float* Mp = M + ((size_t)c * 256) * DD + d;
            const int jl0 = part * 64;
            for (int jl = jl0; jl < jl0 + 64; jl += 8) {   // 8-batched: latency pipelines
                float m0v = ald(&Mp[(size_t)(jl + 0) * DD]);
                float m1v = ald(&Mp[(size_t)(jl + 1) * DD]);
                float m2v = ald(&Mp[(size_t)(jl + 2) * DD]);
                float m3v = ald(&Mp[(size_t)(jl + 3) * DD]);
                float m4v = ald(&Mp[(size_t)(jl + 4) * DD]);
                float m5v = ald(&Mp[(size_t)(jl + 5) * DD]);
                float m6v = ald(&Mp[(size_t)(jl + 6) * DD]);
                float m7v = ald(&Mp[(size_t)(jl + 7) * DD]);
                #pragma unroll
                for (int r = 0; r < 8; ++r) {
                    float4 a0 = *(const float4*)&sm.g1.As[r * 256 + jl];
                    float4 a1 = *(const float4*)&sm.g1.As[r * 256 + jl + 4];
                    acc[r] += a0.x*m0v + a0.y*m1v + a0.z*m2v + a0.w*m3v
                            + a1.x*m4v + a1.y*m5v + a1.z*m6v + a1.w*m7v;
                }
            }
            #pragma unroll
            for (int r = 0; r < 8; ++r) sm.g1.red[part][r][d] = acc[r];
            __syncthreads();
            if (part == 0) {
                if (!fin) {
                    #pragma unroll
                    for (int r = 0; r < 8; ++r) {
                        int i = itile * 8 + r;
                        float v = sm.g1.red[0][r][d] + sm.g1.red[1][r][d]
                                + sm.g1.red[2][r][d] + sm.g1.red[3][r][d];
                        if (c == 0) v += ald(&bFint[i * DD + d]);   // bFint[0] == 0
                        atomicAdd(&Gb[i * DD + d], v);
                    }
                } else {
                    float vsum = 0.f;
                    #pragma unroll
                    for (int r = 0; r < 8; ++r) {
                        int i = itile * 8 + r;
                        float w = (i == 0 || i == TT - 1) ? 0.5f : 1.0f;
                        float v = sm.g1.red[0][r][d] + sm.g1.red[1][r][d]
                                + sm.g1.red[2][r][d] + sm.g1.red[3][r][d];
                        if (c == 0) v += ald(&bFint[i * DD + d]);
                        vsum += w * v;
                    }
                    atomicAdd(&out[d], dt * vsum);
                }
            }
        }
        if (!fin) cbar(bars + 8 * 3, b, tid);
    }
}

extern "C" void kernel_launch(void* const* d_in, const int* in_sizes, int n_in,
                              void* d_out, int out_size, void* d_ws, size_t ws_size,
                              hipStream_t stream) {
    const float* z0  = (const float*)d_in[0];
    const float* t   = (const float*)d_in[1];
    const float* W1  = (const float*)d_in[2];
    const float* b1  = (const float*)d_in[3];
    const float* W2  = (const float*)d_in[4];
    const float* b2  = (const float*)d_in[5];
    const float* Wk1 = (const float*)d_in[6];
    const float* bk1 = (const float*)d_in[7];
    const float* Wk2 = (const float*)d_in[8];
    const float* bk2 = (const float*)d_in[9];
    float* out = (float*)d_out;

    float* ws    = (float*)d_ws;
    float* M     = ws;                       // T*HK*D = 1,048,576 floats (4 MB)
    float* M0    = M     + (size_t)TT*HD;    // 8192
    float* bF0   = M0    + HD;               // 64
    float* Ga    = bF0   + DD;               // T*D = 8192
    float* fbuf  = Ga    + TT*DD;            // 8192
    float* bFb   = fbuf  + TT*DD;            // 8192
    float* bFint = bFb   + TT*DD;            // 8192
    float* Gb    = bFint + TT*DD;            // 8192  (zeroed: it1 atomic accum)
    int*   cnt   = (int*)(Gb + TT*DD);       // 64 ints (zeroed)

    // Zero the accumulator + all counters in one on-stream memset (graph-safe).
    hipMemsetAsync(Gb, 0, TT * DD * sizeof(float) + 64 * sizeof(int), stream);

    mega<<<dim3(NB), dim3(256), 0, stream>>>(
        z0, t, W1, b1, W2, b2, Wk1, bk1, Wk2, bk2,
        M, M0, bF0, Ga, fbuf, bFb, bFint, Gb, cnt, out);
}

// Round 7
// 222.503 us; speedup vs baseline: 1.9478x; 1.1586x over previous
//
#include <hip/hip_runtime.h>

// Problem constants
#define TT 128    // time points
#define DD 64     // state dim
#define HH 256    // f-net hidden
#define HKD 128   // kernel-net hidden
#define HD (HKD*DD)   // 8192

// ---- agent-scope relaxed atomics: used ONLY for same-kernel cross-block data
// ---- (coherent at the coherence point; launch boundaries handle the rest).
static __device__ __forceinline__ float ald(const float* p) {
    return __hip_atomic_load(const_cast<float*>(p), __ATOMIC_RELAXED, __HIP_MEMORY_SCOPE_AGENT);
}
static __device__ __forceinline__ void ast(float* p, float v) {
    __hip_atomic_store(p, v, __ATOMIC_RELAXED, __HIP_MEMORY_SCOPE_AGENT);
}
static __device__ __forceinline__ int aldi(int* p) {
    return __hip_atomic_load(p, __ATOMIC_RELAXED, __HIP_MEMORY_SCOPE_AGENT);
}

// ---------------------------------------------------------------------------
// k_init — 160 blocks.
//   b<32   : f0=f(z0) (redundant), M0 slice via ast, b0 bF0; zero Gb slice;
//            signal m0cnt (r6-proven Pa pattern).
//   b>=32  : G0 row i=b-32: B-row tanh computed WHILE M0 in flight, then
//            flag-wait, dot M0 (ald), write Ga (normal store, next launch).
// ---------------------------------------------------------------------------
__global__ void __launch_bounds__(256)
k_init(const float* __restrict__ z0, const float* __restrict__ t,
       const float* __restrict__ W1, const float* __restrict__ b1,
       const float* __restrict__ W2, const float* __restrict__ b2,
       const float* __restrict__ Wk1, const float* __restrict__ bk1,
       const float* __restrict__ Wk2, const float* __restrict__ bk2,
       float* __restrict__ M0, float* __restrict__ bF0,
       float* __restrict__ Ga, float* __restrict__ Gb, int* m0cnt)
{
    const int b = blockIdx.x, tid = threadIdx.x;
    const int part = tid >> 6, d = tid & 63;
    const float dt = t[1] - t[0];
    __shared__ float red[4][64];
    __shared__ float ys[DD];
    __shared__ float hs[HH];
    __shared__ __attribute__((aligned(16))) float fs[DD];
    __shared__ float Bpart[2][HKD];
    __shared__ float Bs[HKD];

    if (b < 32) {
        // f0 = f(z0)
        if (tid < DD) ys[tid] = z0[tid];
        __syncthreads();
        float acc = b1[tid];
        #pragma unroll 8
        for (int e = 0; e < DD; ++e) acc += ys[e] * W1[e * HH + tid];
        hs[tid] = tanhf(acc);
        __syncthreads();
        {
            float s = 0.f;
            #pragma unroll 8
            for (int h = part * 64; h < part * 64 + 64; ++h) s += hs[h] * W2[h * DD + d];
            red[part][d] = s;
        }
        __syncthreads();
        if (part == 0)
            fs[d] = b2[d] + red[0][d] + red[1][d] + red[2][d] + red[3][d];
        __syncthreads();
        if (b == 0) {   // bF0[d] = bk2[d,:] . f0
            float s = 0.f;
            #pragma unroll
            for (int e = part * 16; e < part * 16 + 16; ++e) s += bk2[d * DD + e] * fs[e];
            red[part][d] = s;
            __syncthreads();
            if (part == 0)
                ast(&bF0[d], red[0][d] + red[1][d] + red[2][d] + red[3][d]);
        }
        // M0 slice (Wk2 row offset == hd*64)
        {
            int hd = b * 256 + tid;
            const float* Wrow = Wk2 + (size_t)hd * DD;
            float a = 0.f;
            #pragma unroll
            for (int e = 0; e < DD; e += 8) {
                float4 wa = *(const float4*)(Wrow + e);
                float4 wb = *(const float4*)(Wrow + e + 4);
                float4 fa = *(const float4*)&fs[e];
                float4 fb = *(const float4*)&fs[e + 4];
                a += fa.x*wa.x + fa.y*wa.y + fa.z*wa.z + fa.w*wa.w
                   + fb.x*wb.x + fb.y*wb.y + fb.z*wb.z + fb.w*wb.w;
            }
            ast(&M0[hd], a);
        }
        Gb[b * 256 + tid] = 0.f;          // zero it1's atomic accumulator
        __syncthreads();                   // drain this block's ast stores
        asm volatile("" ::: "memory");
        if (tid == 0)
            __hip_atomic_fetch_add(m0cnt, 1, __ATOMIC_RELAXED, __HIP_MEMORY_SCOPE_AGENT);
        return;
    }

    // ---- G0 row i (overlaps M0)
    const int i = b - 32;
    {
        const int h = tid & 127, half = tid >> 7;
        float bsum = 0.f;
        if (i > 0) {
            const float wk0 = Wk1[h], wk1v = Wk1[HKD + h], bk = bk1[h];
            const float ti = t[i];
            for (int j = half; j <= i; j += 2) {
                float w = dt * ((j == 0 || j == i) ? 0.5f : 1.0f);
                bsum += w * tanhf(ti * wk0 + t[j] * wk1v + bk);
            }
        }
        Bpart[half][h] = bsum;
    }
    __syncthreads();
    if (tid < HKD) Bs[tid] = Bpart[0][tid] + Bpart[1][tid];
    if (tid == 0) { while (aldi(m0cnt) < 32) __builtin_amdgcn_s_sleep(2); }
    asm volatile("" ::: "memory");
    __syncthreads();
    float a = 0.f;
    #pragma unroll 8
    for (int h2 = part * 32; h2 < part * 32 + 32; ++h2)
        a += Bs[h2] * ald(&M0[h2 * DD + d]);
    red[part][d] = a;
    __syncthreads();
    if (part == 0) {
        float g = red[0][d] + red[1][d] + red[2][d] + red[3][d];
        g += dt * (float)i * ald(&bF0[d]);
        Ga[i * DD + d] = (i == 0) ? 0.f : g;   // normal store: next launch reads
    }
}

// ---------------------------------------------------------------------------
// k_FM — flag-fused F+M, 512 blocks (all resident at 2/CU; F blocks 0-127
// always finish their F before any spin -> deadlock-free at any residency).
//   b<128: F_j (r0-proven): y_j = z0+dt*trap(Gin), f_j = MLP; fbuf via ast,
//          bFb normal store; signal ftile[j>>3] (padded counters).
//   all  : M-unit u=b (r0 k_M): wait 8 F flags of tile u>>5, stage f via ald,
//          M slice with Wk2 (normal cached), M normal store (next launch).
// ---------------------------------------------------------------------------
__global__ void __launch_bounds__(256)
k_FM(const float* __restrict__ Gin, const float* __restrict__ z0,
     const float* __restrict__ t,
     const float* __restrict__ W1, const float* __restrict__ b1,
     const float* __restrict__ W2, const float* __restrict__ b2,
     const float* __restrict__ bk2, const float* __restrict__ Wk2,
     float* __restrict__ fbuf, float* __restrict__ bFb,
     float* __restrict__ M, int* ftile,
     float* __restrict__ out, int seed_out)
{
    const int b = blockIdx.x, tid = threadIdx.x;
    const int part = tid >> 6, d = tid & 63;
    __shared__ float red[4][64];
    __shared__ float ys[DD];
    __shared__ float hs[HH];
    __shared__ __attribute__((aligned(16))) float Fs[8][DD];
    const float dt = t[1] - t[0];

    if (b < TT) {
        const int j = b;
        // y_j = z0 + dt*trap(Gin[0..j])   (Gin from previous launch: cached)
        float s = 0.f;
        if (j > 0) {
            for (int jp = part; jp <= j; jp += 4) {
                float w = (jp == 0 || jp == j) ? 0.5f : 1.0f;
                s += w * Gin[jp * DD + d];
            }
        }
        red[part][d] = s;
        __syncthreads();
        if (part == 0)
            ys[d] = z0[d] + dt * (red[0][d] + red[1][d] + red[2][d] + red[3][d]);
        __syncthreads();
        // f_j = tanh(y@W1+b1)@W2+b2
        float acc = b1[tid];
        #pragma unroll 8
        for (int e = 0; e < DD; ++e) acc += ys[e] * W1[e * HH + tid];
        hs[tid] = tanhf(acc);
        __syncthreads();
        {
            float s2 = 0.f;
            #pragma unroll 8
            for (int h = part * 64; h < part * 64 + 64; ++h) s2 += hs[h] * W2[h * DD + d];
            red[part][d] = s2;
        }
        __syncthreads();
        if (part == 0) {
            float fv = b2[d] + red[0][d] + red[1][d] + red[2][d] + red[3][d];
            ast(&fbuf[j * DD + d], fv);    // same-kernel consumer -> agent store
            ys[d] = fv;                    // reuse ys as fs for bk2 dot
        }
        __syncthreads();
        {
            float s2 = 0.f;
            #pragma unroll
            for (int e = part * 16; e < part * 16 + 16; ++e) s2 += bk2[d * DD + e] * ys[e];
            red[part][d] = s2;
            __syncthreads();
            if (part == 0)
                bFb[j * DD + d] = red[0][d] + red[1][d] + red[2][d] + red[3][d]; // next launch
        }
        __syncthreads();                   // drain ast stores (all waves vmcnt 0)
        asm volatile("" ::: "memory");
        if (tid == 0)
            __hip_atomic_fetch_add(&ftile[(j >> 3) * 16], 1,
                                   __ATOMIC_RELAXED, __HIP_MEMORY_SCOPE_AGENT);
    }

    // ---- M-unit u = b: hd-chunk (b&31)*256, j-tile (b>>5)*8
    const int tilei = b >> 5;
    const int hd = (b & 31) * 256 + tid;
    const int j0 = tilei * 8;
    if (tid == 0) {
        while (aldi(&ftile[tilei * 16]) < 8) __builtin_amdgcn_s_sleep(2);
    }
    asm volatile("" ::: "memory");
    __syncthreads();
    for (int k2 = tid; k2 < 8 * DD; k2 += 256)
        Fs[k2 >> 6][k2 & 63] = ald(&fbuf[j0 * DD + k2]);
    __syncthreads();
    float acc[8] = {0.f,0.f,0.f,0.f,0.f,0.f,0.f,0.f};
    const float* Wrow = Wk2 + (size_t)hd * DD;
    for (int e = 0; e < DD; e += 8) {
        float4 wa = *(const float4*)(Wrow + e);
        float4 wb = *(const float4*)(Wrow + e + 4);
        #pragma unroll
        for (int r = 0; r < 8; ++r) {
            float4 f0 = *(const float4*)&Fs[r][e];
            float4 f1 = *(const float4*)&Fs[r][e + 4];
            acc[r] += f0.x*wa.x + f0.y*wa.y + f0.z*wa.z + f0.w*wa.w
                    + f1.x*wb.x + f1.y*wb.y + f1.z*wb.z + f1.w*wb.w;
        }
    }
    #pragma unroll
    for (int r = 0; r < 8; ++r) M[(size_t)(j0 + r) * HD + hd] = acc[r];  // next launch

    if (seed_out && b == 128 && tid < DD) out[tid] = z0[tid];   // consumed next launch
}

// ---------------------------------------------------------------------------
// k_G1a — fused G1+Gfin (r5-proven math; A-tile tanh'd on the fly, r0-proven).
// grid (16 itiles, 64 chunks), active iff c<=4*itile+3 (544 blocks).
// final==0: atomicAdd partials into Gout (pre-zeroed) + bF running-scan term.
// final==1: fold output trapezoid into out (seeded=z0 by preceding k_FM).
// ---------------------------------------------------------------------------
__global__ void __launch_bounds__(256)
k_G1a(const float* __restrict__ t, const float* __restrict__ Wk1,
      const float* __restrict__ bk1, const float* __restrict__ M,
      const float* __restrict__ bF,
      float* __restrict__ Gout, float* __restrict__ out, int final_it)
{
    const int itile = blockIdx.x, c = blockIdx.y;
    if (c > 4 * itile + 3) return;
    __shared__ __attribute__((aligned(16))) float As[8 * 256];
    __shared__ float red[4][8][64];
    const int tid = threadIdx.x, part = tid >> 6, d = tid & 63;
    const float dt = t[1] - t[0];

    {   // A-tile on the fly (r0 k_G1)
        const int h = tid & 127;
        const int j = 2 * c + (tid >> 7);
        const float wk0 = Wk1[h], wk1v = Wk1[HKD + h], bk = bk1[h];
        const float tj = t[j];
        #pragma unroll
        for (int k = 0; k < 8; ++k) {
            int i = itile * 8 + k;
            float w = (i == 0 || j > i) ? 0.f : dt * ((j == 0 || j == i) ? 0.5f : 1.0f);
            As[k * 256 + tid] = w * tanhf(t[i] * wk0 + tj * wk1v + bk);
        }
    }
    __syncthreads();

    float acc[8] = {0.f,0.f,0.f,0.f,0.f,0.f,0.f,0.f};
    const float* Mp = M + ((size_t)c * 256) * DD + d;
    const int jl0 = part * 64;
    for (int jl = jl0; jl < jl0 + 64; jl += 8) {
        float m0 = Mp[(size_t)(jl + 0) * DD];
        float m1 = Mp[(size_t)(jl + 1) * DD];
        float m2 = Mp[(size_t)(jl + 2) * DD];
        float m3 = Mp[(size_t)(jl + 3) * DD];
        float m4 = Mp[(size_t)(jl + 4) * DD];
        float m5 = Mp[(size_t)(jl + 5) * DD];
        float m6 = Mp[(size_t)(jl + 6) * DD];
        float m7 = Mp[(size_t)(jl + 7) * DD];
        #pragma unroll
        for (int r = 0; r < 8; ++r) {
            float4 a0 = *(const float4*)&As[r * 256 + jl];
            float4 a1 = *(const float4*)&As[r * 256 + jl + 4];
            acc[r] += a0.x*m0 + a0.y*m1 + a0.z*m2 + a0.w*m3
                    + a1.x*m4 + a1.y*m5 + a1.z*m6 + a1.w*m7;
        }
    }
    #pragma unroll
    for (int r = 0; r < 8; ++r) red[part][r][d] = acc[r];
    __syncthreads();
    if (part == 0) {
        if (!final_it) {
            #pragma unroll
            for (int r = 0; r < 8; ++r) {
                float v = red[0][r][d] + red[1][r][d] + red[2][r][d] + red[3][r][d];
                atomicAdd(&Gout[(itile * 8 + r) * DD + d], v);
            }
            if (c == 0) {   // dt*trap(bF[0..i]) term, once per row
                const int i0 = itile * 8;
                float run = 0.5f * bF[d];
                int p = 0;
                for (int r = 0; r < 8; ++r) {
                    int i = i0 + r;
                    if (i == 0) continue;
                    while (p < i - 1) { ++p; run += bF[p * DD + d]; }
                    float term = dt * (run + 0.5f * bF[i * DD + d]);
                    atomicAdd(&Gout[i * DD + d], term);
                }
            }
        } else {
            float vsum = 0.f;
            #pragma unroll
            for (int r = 0; r < 8; ++r) {
                int i = itile * 8 + r;
                float w = (i == 0 || i == TT - 1) ? 0.5f : 1.0f;
                vsum += w * (red[0][r][d] + red[1][r][d] + red[2][r][d] + red[3][r][d]);
            }
            if (c == 0) {
                const int i0 = itile * 8;
                float run = 0.5f * bF[d];
                int p = 0;
                for (int r = 0; r < 8; ++r) {
                    int i = i0 + r;
                    if (i == 0) continue;
                    while (p < i - 1) { ++p; run += bF[p * DD + d]; }
                    float term = dt * (run + 0.5f * bF[i * DD + d]);
                    float w = (i == TT - 1) ? 0.5f : 1.0f;   // i>0 here
                    vsum += w * term;
                }
            }
            atomicAdd(&out[d], dt * vsum);
        }
    }
}

extern "C" void kernel_launch(void* const* d_in, const int* in_sizes, int n_in,
                              void* d_out, int out_size, void* d_ws, size_t ws_size,
                              hipStream_t stream) {
    const float* z0  = (const float*)d_in[0];
    const float* t   = (const float*)d_in[1];
    const float* W1  = (const float*)d_in[2];
    const float* b1  = (const float*)d_in[3];
    const float* W2  = (const float*)d_in[4];
    const float* b2  = (const float*)d_in[5];
    const float* Wk1 = (const float*)d_in[6];
    const float* bk1 = (const float*)d_in[7];
    const float* Wk2 = (const float*)d_in[8];
    const float* bk2 = (const float*)d_in[9];
    float* out = (float*)d_out;

    float* ws   = (float*)d_ws;
    float* M    = ws;                       // T*HK*D = 1,048,576 floats (4 MB)
    float* M0   = M    + (size_t)TT*HD;     // 8192
    float* bF0  = M0   + HD;                // 64
    float* Ga   = bF0  + DD;                // T*D
    float* Gb   = Ga   + TT*DD;             // T*D (zeroed by k_init)
    float* fbuf = Gb   + TT*DD;             // T*D
    float* bFb  = fbuf + TT*DD;             // T*D
    int*   cnt  = (int*)(bFb + TT*DD);      // m0cnt(16) + ftileA(256) + ftileB(256)

    int* m0cnt  = cnt;
    int* ftileA = cnt + 16;                 // 16 counters, 64B stride
    int* ftileB = cnt + 16 + 256;

    hipMemsetAsync(cnt, 0, 528 * sizeof(int), stream);

    // 5 launches, no grid barriers (in-kernel barrier ~30us vs launch gap ~10us).
    k_init<<<160, 256, 0, stream>>>(z0, t, W1, b1, W2, b2, Wk1, bk1, Wk2, bk2,
                                    M0, bF0, Ga, Gb, m0cnt);
    k_FM<<<512, 256, 0, stream>>>(Ga, z0, t, W1, b1, W2, b2, bk2, Wk2,
                                  fbuf, bFb, M, ftileA, out, 0);
    k_G1a<<<dim3(16, 64), 256, 0, stream>>>(t, Wk1, bk1, M, bFb, Gb, out, 0);
    k_FM<<<512, 256, 0, stream>>>(Gb, z0, t, W1, b1, W2, b2, bk2, Wk2,
                                  fbuf, bFb, M, ftileB, out, 1);
    k_G1a<<<dim3(16, 64), 256, 0, stream>>>(t, Wk1, bk1, M, bFb, Gb, out, 1);
}

// Round 8
// 187.268 us; speedup vs baseline: 2.3143x; 1.1882x over previous
//
#include <hip/hip_runtime.h>

// Problem constants
#define TT 128    // time points
#define DD 64     // state dim
#define HH 256    // f-net hidden
#define HKD 128   // kernel-net hidden
#define HD (HKD*DD)   // 8192

// ---- agent-scope relaxed atomics: used ONLY for same-kernel cross-block data
static __device__ __forceinline__ float ald(const float* p) {
    return __hip_atomic_load(const_cast<float*>(p), __ATOMIC_RELAXED, __HIP_MEMORY_SCOPE_AGENT);
}
static __device__ __forceinline__ void ast(float* p, float v) {
    __hip_atomic_store(p, v, __ATOMIC_RELAXED, __HIP_MEMORY_SCOPE_AGENT);
}
static __device__ __forceinline__ int aldi(int* p) {
    return __hip_atomic_load(p, __ATOMIC_RELAXED, __HIP_MEMORY_SCOPE_AGENT);
}

// ---------------------------------------------------------------------------
// k_init — 160 blocks (r7-proven, unchanged).
//   b<32   : f0=f(z0), M0 slice via ast, b0 bF0; zero Gb slice; signal m0cnt.
//   b>=32  : G0 row i=b-32: B-row tanh WHILE M0 in flight, flag-wait, dot M0.
// ---------------------------------------------------------------------------
__global__ void __launch_bounds__(256)
k_init(const float* __restrict__ z0, const float* __restrict__ t,
       const float* __restrict__ W1, const float* __restrict__ b1,
       const float* __restrict__ W2, const float* __restrict__ b2,
       const float* __restrict__ Wk1, const float* __restrict__ bk1,
       const float* __restrict__ Wk2, const float* __restrict__ bk2,
       float* __restrict__ M0, float* __restrict__ bF0,
       float* __restrict__ Ga, float* __restrict__ Gb, int* m0cnt)
{
    const int b = blockIdx.x, tid = threadIdx.x;
    const int part = tid >> 6, d = tid & 63;
    const float dt = t[1] - t[0];
    __shared__ float red[4][64];
    __shared__ float ys[DD];
    __shared__ float hs[HH];
    __shared__ __attribute__((aligned(16))) float fs[DD];
    __shared__ float Bpart[2][HKD];
    __shared__ float Bs[HKD];

    if (b < 32) {
        if (tid < DD) ys[tid] = z0[tid];
        __syncthreads();
        float acc = b1[tid];
        #pragma unroll 8
        for (int e = 0; e < DD; ++e) acc += ys[e] * W1[e * HH + tid];
        hs[tid] = tanhf(acc);
        __syncthreads();
        {
            float s = 0.f;
            #pragma unroll 8
            for (int h = part * 64; h < part * 64 + 64; ++h) s += hs[h] * W2[h * DD + d];
            red[part][d] = s;
        }
        __syncthreads();
        if (part == 0)
            fs[d] = b2[d] + red[0][d] + red[1][d] + red[2][d] + red[3][d];
        __syncthreads();
        if (b == 0) {
            float s = 0.f;
            #pragma unroll
            for (int e = part * 16; e < part * 16 + 16; ++e) s += bk2[d * DD + e] * fs[e];
            red[part][d] = s;
            __syncthreads();
            if (part == 0)
                ast(&bF0[d], red[0][d] + red[1][d] + red[2][d] + red[3][d]);
        }
        {
            int hd = b * 256 + tid;
            const float* Wrow = Wk2 + (size_t)hd * DD;
            float a = 0.f;
            #pragma unroll
            for (int e = 0; e < DD; e += 8) {
                float4 wa = *(const float4*)(Wrow + e);
                float4 wb = *(const float4*)(Wrow + e + 4);
                float4 fa = *(const float4*)&fs[e];
                float4 fb = *(const float4*)&fs[e + 4];
                a += fa.x*wa.x + fa.y*wa.y + fa.z*wa.z + fa.w*wa.w
                   + fb.x*wb.x + fb.y*wb.y + fb.z*wb.z + fb.w*wb.w;
            }
            ast(&M0[hd], a);
        }
        Gb[b * 256 + tid] = 0.f;          // zero it1's atomic accumulator
        __syncthreads();
        asm volatile("" ::: "memory");
        if (tid == 0)
            __hip_atomic_fetch_add(m0cnt, 1, __ATOMIC_RELAXED, __HIP_MEMORY_SCOPE_AGENT);
        return;
    }

    const int i = b - 32;
    {
        const int h = tid & 127, half = tid >> 7;
        float bsum = 0.f;
        if (i > 0) {
            const float wk0 = Wk1[h], wk1v = Wk1[HKD + h], bk = bk1[h];
            const float ti = t[i];
            for (int j = half; j <= i; j += 2) {
                float w = dt * ((j == 0 || j == i) ? 0.5f : 1.0f);
                bsum += w * tanhf(ti * wk0 + t[j] * wk1v + bk);
            }
        }
        Bpart[half][h] = bsum;
    }
    __syncthreads();
    if (tid < HKD) Bs[tid] = Bpart[0][tid] + Bpart[1][tid];
    if (tid == 0) { while (aldi(m0cnt) < 32) __builtin_amdgcn_s_sleep(2); }
    asm volatile("" ::: "memory");
    __syncthreads();
    float a = 0.f;
    #pragma unroll 8
    for (int h2 = part * 32; h2 < part * 32 + 32; ++h2)
        a += Bs[h2] * ald(&M0[h2 * DD + d]);
    red[part][d] = a;
    __syncthreads();
    if (part == 0) {
        float g = red[0][d] + red[1][d] + red[2][d] + red[3][d];
        g += dt * (float)i * ald(&bF0[d]);
        Ga[i * DD + d] = (i == 0) ? 0.f : g;
    }
}

// ---------------------------------------------------------------------------
// k_FM — flag-fused F+M (r7-proven) + NEW: block 511 computes
// bFint[i,d] = dt*trap(bFb[0..i],d) via LDS scan (kills k_G1a's serial-scan
// straggler). bFb now ast (same-kernel consumer).
// ---------------------------------------------------------------------------
__global__ void __launch_bounds__(256)
k_FM(const float* __restrict__ Gin, const float* __restrict__ z0,
     const float* __restrict__ t,
     const float* __restrict__ W1, const float* __restrict__ b1,
     const float* __restrict__ W2, const float* __restrict__ b2,
     const float* __restrict__ bk2, const float* __restrict__ Wk2,
     float* __restrict__ fbuf, float* __restrict__ bFb,
     float* __restrict__ M, int* ftile, float* __restrict__ bFint,
     float* __restrict__ out, int seed_out)
{
    const int b = blockIdx.x, tid = threadIdx.x;
    const int part = tid >> 6, d = tid & 63;
    __shared__ float red[4][64];
    __shared__ float ys[DD];
    __shared__ float hs[HH];
    __shared__ __attribute__((aligned(16))) float Fs[8][DD];
    __shared__ float scanb[TT][DD];          // 32 KB, used only by block 511
    const float dt = t[1] - t[0];

    if (b < TT) {
        const int j = b;
        float s = 0.f;
        if (j > 0) {
            for (int jp = part; jp <= j; jp += 4) {
                float w = (jp == 0 || jp == j) ? 0.5f : 1.0f;
                s += w * Gin[jp * DD + d];
            }
        }
        red[part][d] = s;
        __syncthreads();
        if (part == 0)
            ys[d] = z0[d] + dt * (red[0][d] + red[1][d] + red[2][d] + red[3][d]);
        __syncthreads();
        float acc = b1[tid];
        #pragma unroll 8
        for (int e = 0; e < DD; ++e) acc += ys[e] * W1[e * HH + tid];
        hs[tid] = tanhf(acc);
        __syncthreads();
        {
            float s2 = 0.f;
            #pragma unroll 8
            for (int h = part * 64; h < part * 64 + 64; ++h) s2 += hs[h] * W2[h * DD + d];
            red[part][d] = s2;
        }
        __syncthreads();
        if (part == 0) {
            float fv = b2[d] + red[0][d] + red[1][d] + red[2][d] + red[3][d];
            ast(&fbuf[j * DD + d], fv);
            ys[d] = fv;                    // reuse ys as fs for bk2 dot
        }
        __syncthreads();
        {
            float s2 = 0.f;
            #pragma unroll
            for (int e = part * 16; e < part * 16 + 16; ++e) s2 += bk2[d * DD + e] * ys[e];
            red[part][d] = s2;
            __syncthreads();
            if (part == 0)
                ast(&bFb[j * DD + d], red[0][d] + red[1][d] + red[2][d] + red[3][d]);
        }
        __syncthreads();                   // drain ast stores
        asm volatile("" ::: "memory");
        if (tid == 0)
            __hip_atomic_fetch_add(&ftile[(j >> 3) * 16], 1,
                                   __ATOMIC_RELAXED, __HIP_MEMORY_SCOPE_AGENT);
    }

    // ---- M-unit u = b
    const int tilei = b >> 5;
    const int hd = (b & 31) * 256 + tid;
    const int j0 = tilei * 8;
    if (tid == 0) {
        while (aldi(&ftile[tilei * 16]) < 8) __builtin_amdgcn_s_sleep(2);
    }
    asm volatile("" ::: "memory");
    __syncthreads();
    for (int k2 = tid; k2 < 8 * DD; k2 += 256)
        Fs[k2 >> 6][k2 & 63] = ald(&fbuf[j0 * DD + k2]);
    __syncthreads();
    float acc[8] = {0.f,0.f,0.f,0.f,0.f,0.f,0.f,0.f};
    const float* Wrow = Wk2 + (size_t)hd * DD;
    for (int e = 0; e < DD; e += 8) {
        float4 wa = *(const float4*)(Wrow + e);
        float4 wb = *(const float4*)(Wrow + e + 4);
        #pragma unroll
        for (int r = 0; r < 8; ++r) {
            float4 f0 = *(const float4*)&Fs[r][e];
            float4 f1 = *(const float4*)&Fs[r][e + 4];
            acc[r] += f0.x*wa.x + f0.y*wa.y + f0.z*wa.z + f0.w*wa.w
                    + f1.x*wb.x + f1.y*wb.y + f1.z*wb.z + f1.w*wb.w;
        }
    }
    #pragma unroll
    for (int r = 0; r < 8; ++r) M[(size_t)(j0 + r) * HD + hd] = acc[r];  // next launch

    if (seed_out && b == 128 && tid < DD) out[tid] = z0[tid];

    // ---- block 511: bFint = dt*trap-prefix of bFb (consumed next launch).
    // F-blocks never spin before signaling -> deadlock-free.
    if (b == 511) {
        if (tid < 16) { while (aldi(&ftile[tid * 16]) < 8) __builtin_amdgcn_s_sleep(2); }
        asm volatile("" ::: "memory");
        __syncthreads();
        for (int idx = tid; idx < TT * DD; idx += 256)
            scanb[idx >> 6][idx & 63] = ald(&bFb[idx]);
        __syncthreads();
        if (tid < DD) {
            float run = 0.5f * scanb[0][tid];
            bFint[tid] = 0.f;                       // i=0: zero-length integral
            for (int i = 1; i < TT; ++i) {
                float v = scanb[i][tid];
                bFint[i * DD + tid] = dt * (run + 0.5f * v);
                run += v;
            }
        }
    }
}

// ---------------------------------------------------------------------------
// k_G1a — fused G1+Gfin. grid (16 itiles, 64 chunks), active iff c<=4*itile+3.
// NEW: 64-deep register-batched M loads (one latency exposure per wave instead
// of 8); serial bF scan replaced by precomputed bFint.
// ---------------------------------------------------------------------------
__global__ void __launch_bounds__(256)
k_G1a(const float* __restrict__ t, const float* __restrict__ Wk1,
      const float* __restrict__ bk1, const float* __restrict__ M,
      const float* __restrict__ bFint,
      float* __restrict__ Gout, float* __restrict__ out, int final_it)
{
    const int itile = blockIdx.x, c = blockIdx.y;
    if (c > 4 * itile + 3) return;
    __shared__ __attribute__((aligned(16))) float As[8 * 256];
    __shared__ float red[4][8][64];
    const int tid = threadIdx.x, part = tid >> 6, d = tid & 63;
    const float dt = t[1] - t[0];
    const int jl0 = part * 64;

    // Issue the 64 M loads FIRST (independent, fully unrolled -> deep vmcnt
    // pipelining; the tanh A-tile below computes while they are in flight).
    const float* Mp = M + ((size_t)c * 256 + jl0) * DD + d;
    float m[64];
    #pragma unroll
    for (int k = 0; k < 64; ++k) m[k] = Mp[(size_t)k * DD];

    {   // A-tile on the fly
        const int h = tid & 127;
        const int j = 2 * c + (tid >> 7);
        const float wk0 = Wk1[h], wk1v = Wk1[HKD + h], bk = bk1[h];
        const float tj = t[j];
        #pragma unroll
        for (int k = 0; k < 8; ++k) {
            int i = itile * 8 + k;
            float w = (i == 0 || j > i) ? 0.f : dt * ((j == 0 || j == i) ? 0.5f : 1.0f);
            As[k * 256 + tid] = w * tanhf(t[i] * wk0 + tj * wk1v + bk);
        }
    }
    __syncthreads();

    float acc[8];
    const float4* As4 = (const float4*)As;
    #pragma unroll
    for (int r = 0; r < 8; ++r) {
        float s = 0.f;
        #pragma unroll
        for (int k4 = 0; k4 < 16; ++k4) {
            float4 a = As4[r * 64 + (jl0 >> 2) + k4];
            s += a.x * m[k4 * 4] + a.y * m[k4 * 4 + 1]
               + a.z * m[k4 * 4 + 2] + a.w * m[k4 * 4 + 3];
        }
        acc[r] = s;
    }
    #pragma unroll
    for (int r = 0; r < 8; ++r) red[part][r][d] = acc[r];
    __syncthreads();
    if (part == 0) {
        if (!final_it) {
            #pragma unroll
            for (int r = 0; r < 8; ++r) {
                int i = itile * 8 + r;
                float v = red[0][r][d] + red[1][r][d] + red[2][r][d] + red[3][r][d];
                if (c == 0) v += ald(&bFint[i * DD + d]);   // bFint[0] == 0
                atomicAdd(&Gout[i * DD + d], v);
            }
        } else {
            float vsum = 0.f;
            #pragma unroll
            for (int r = 0; r < 8; ++r) {
                int i = itile * 8 + r;
                float w = (i == 0 || i == TT - 1) ? 0.5f : 1.0f;
                float v = red[0][r][d] + red[1][r][d] + red[2][r][d] + red[3][r][d];
                if (c == 0) v += ald(&bFint[i * DD + d]);
                vsum += w * v;
            }
            atomicAdd(&out[d], dt * vsum);
        }
    }
}

extern "C" void kernel_launch(void* const* d_in, const int* in_sizes, int n_in,
                              void* d_out, int out_size, void* d_ws, size_t ws_size,
                              hipStream_t stream) {
    const float* z0  = (const float*)d_in[0];
    const float* t   = (const float*)d_in[1];
    const float* W1  = (const float*)d_in[2];
    const float* b1  = (const float*)d_in[3];
    const float* W2  = (const float*)d_in[4];
    const float* b2  = (const float*)d_in[5];
    const float* Wk1 = (const float*)d_in[6];
    const float* bk1 = (const float*)d_in[7];
    const float* Wk2 = (const float*)d_in[8];
    const float* bk2 = (const float*)d_in[9];
    float* out = (float*)d_out;

    float* ws    = (float*)d_ws;
    float* M     = ws;                       // T*HK*D = 1,048,576 floats (4 MB)
    float* M0    = M     + (size_t)TT*HD;    // 8192
    float* bF0   = M0    + HD;               // 64
    float* Ga    = bF0   + DD;               // T*D
    float* Gb    = Ga    + TT*DD;            // T*D (zeroed by k_init)
    float* fbuf  = Gb    + TT*DD;            // T*D
    float* bFb   = fbuf  + TT*DD;            // T*D
    float* bFint = bFb   + TT*DD;            // T*D
    int*   cnt   = (int*)(bFint + TT*DD);    // m0cnt(16) + ftileA(256) + ftileB(256)

    int* m0cnt  = cnt;
    int* ftileA = cnt + 16;
    int* ftileB = cnt + 16 + 256;

    hipMemsetAsync(cnt, 0, 528 * sizeof(int), stream);

    // 5 launches, no grid barriers.
    k_init<<<160, 256, 0, stream>>>(z0, t, W1, b1, W2, b2, Wk1, bk1, Wk2, bk2,
                                    M0, bF0, Ga, Gb, m0cnt);
    k_FM<<<512, 256, 0, stream>>>(Ga, z0, t, W1, b1, W2, b2, bk2, Wk2,
                                  fbuf, bFb, M, ftileA, bFint, out, 0);
    k_G1a<<<dim3(16, 64), 256, 0, stream>>>(t, Wk1, bk1, M, bFint, Gb, out, 0);
    k_FM<<<512, 256, 0, stream>>>(Gb, z0, t, W1, b1, W2, b2, bk2, Wk2,
                                  fbuf, bFb, M, ftileB, bFint, out, 1);
    k_G1a<<<dim3(16, 64), 256, 0, stream>>>(t, Wk1, bk1, M, bFint, Gb, out, 1);
}